// Round 1
// baseline (149.003 us; speedup 1.0000x reference)
//
#include <hip/hip_runtime.h>

#define NB 32768
#define NF 256
#define H1 16
#define H2 8
#define R_PER_BLOCK 64
#define CHUNK 16

__device__ __forceinline__ float elu_f(float v) {
    return v > 0.0f ? v : (__expf(v) - 1.0f);
}

__global__ __launch_bounds__(256, 2)
void nul_kernel(const float* __restrict__ x,
                const float* __restrict__ W1, const float* __restrict__ b1,
                const float* __restrict__ W2, const float* __restrict__ b2,
                const float* __restrict__ W3, const float* __restrict__ b3,
                const float* __restrict__ theta, const float* __restrict__ bias,
                float* __restrict__ y_out, float* __restrict__ w_out,
                float* __restrict__ z_out) {
    const int f = threadIdx.x;              // one thread per feature
    const int rowBase = blockIdx.x * R_PER_BLOCK;

    // ---- per-feature params -> registers (float4 loads) ----
    float w1v[H1], b1v[H1], w2v[H1 * H2], b2v[H2], w3v[H2];
    {
        const float4* p = reinterpret_cast<const float4*>(W1 + f * H1);
        #pragma unroll
        for (int i = 0; i < H1 / 4; ++i) {
            float4 v = p[i];
            w1v[4*i] = v.x; w1v[4*i+1] = v.y; w1v[4*i+2] = v.z; w1v[4*i+3] = v.w;
        }
    }
    {
        const float4* p = reinterpret_cast<const float4*>(b1 + f * H1);
        #pragma unroll
        for (int i = 0; i < H1 / 4; ++i) {
            float4 v = p[i];
            b1v[4*i] = v.x; b1v[4*i+1] = v.y; b1v[4*i+2] = v.z; b1v[4*i+3] = v.w;
        }
    }
    {
        const float4* p = reinterpret_cast<const float4*>(W2 + f * H1 * H2);
        #pragma unroll
        for (int i = 0; i < (H1 * H2) / 4; ++i) {
            float4 v = p[i];
            w2v[4*i] = v.x; w2v[4*i+1] = v.y; w2v[4*i+2] = v.z; w2v[4*i+3] = v.w;
        }
    }
    {
        const float4* p = reinterpret_cast<const float4*>(b2 + f * H2);
        #pragma unroll
        for (int i = 0; i < H2 / 4; ++i) {
            float4 v = p[i];
            b2v[4*i] = v.x; b2v[4*i+1] = v.y; b2v[4*i+2] = v.z; b2v[4*i+3] = v.w;
        }
    }
    {
        const float4* p = reinterpret_cast<const float4*>(W3 + f * H2);
        #pragma unroll
        for (int i = 0; i < H2 / 4; ++i) {
            float4 v = p[i];
            w3v[4*i] = v.x; w3v[4*i+1] = v.y; w3v[4*i+2] = v.z; w3v[4*i+3] = v.w;
        }
    }
    const float b3v   = b3[f];
    const float th    = theta[f];
    const float wv    = logf(1.0f + __expf(th));   // softplus
    const float biasv = bias[0];

    if (blockIdx.x == 0) w_out[f] = wv;            // weights output once

    __shared__ float P[CHUNK][NF + 1];             // +1 pad vs bank conflicts

    // rotating prefetch of x
    float xnext = x[rowBase * NF + f];

    for (int c = 0; c < R_PER_BLOCK; c += CHUNK) {
        #pragma unroll 1
        for (int r = 0; r < CHUNK; ++r) {
            const int row = rowBase + c + r;
            const float xv = xnext;
            int nrow = row + 1; if (nrow >= NB) nrow = row;
            xnext = x[nrow * NF + f];              // prefetch next row

            float h1v[H1];
            #pragma unroll
            for (int h = 0; h < H1; ++h)
                h1v[h] = elu_f(fmaf(xv, w1v[h], b1v[h]));

            float acc[H2];
            #pragma unroll
            for (int k = 0; k < H2; ++k) acc[k] = b2v[k];
            #pragma unroll
            for (int h = 0; h < H1; ++h) {
                #pragma unroll
                for (int k = 0; k < H2; ++k)
                    acc[k] = fmaf(h1v[h], w2v[h * H2 + k], acc[k]);
            }

            float z = b3v;
            #pragma unroll
            for (int k = 0; k < H2; ++k)
                z = fmaf(elu_f(acc[k]), w3v[k], z);

            z_out[row * NF + f] = z;               // coalesced Z write
            P[r][f] = wv * z;                      // stage for y reduction
        }
        __syncthreads();
        {
            // 16 rows x 256 partials, 16 threads per row
            const int rr = threadIdx.x >> 4;       // row within chunk
            const int l  = threadIdx.x & 15;
            float s = 0.0f;
            #pragma unroll
            for (int i = 0; i < 16; ++i) s += P[rr][i * 16 + l];
            #pragma unroll
            for (int o = 8; o > 0; o >>= 1) s += __shfl_down(s, o, 16);
            if (l == 0) y_out[rowBase + c + rr] = s + biasv;
        }
        __syncthreads();
    }
}

extern "C" void kernel_launch(void* const* d_in, const int* in_sizes, int n_in,
                              void* d_out, int out_size, void* d_ws, size_t ws_size,
                              hipStream_t stream) {
    const float* x     = (const float*)d_in[0];
    const float* W1    = (const float*)d_in[1];
    const float* b1    = (const float*)d_in[2];
    const float* W2    = (const float*)d_in[3];
    const float* b2    = (const float*)d_in[4];
    const float* W3    = (const float*)d_in[5];
    const float* b3    = (const float*)d_in[6];
    const float* theta = (const float*)d_in[7];
    const float* bias  = (const float*)d_in[8];

    float* y_out = (float*)d_out;                  // [32768]
    float* w_out = y_out + NB;                     // [256]
    float* z_out = w_out + NF;                     // [32768*256]

    nul_kernel<<<NB / R_PER_BLOCK, NF, 0, stream>>>(
        x, W1, b1, W2, b2, W3, b3, theta, bias, y_out, w_out, z_out);
}